// Round 12
// baseline (1371.959 us; speedup 1.0000x reference)
//
#include <hip/hip_runtime.h>

// Problem constants (from reference setup_inputs)
#define NVOX   4096   // B voxels
#define NMEAS  256    // M measurements
#define NATOMS 512    // K atoms
#define NITER  30

typedef __attribute__((ext_vector_type(8))) short s8v;   // 8 bf16 (4 VGPR) MFMA frag
typedef __attribute__((ext_vector_type(4))) short s4v;
typedef __attribute__((ext_vector_type(4))) float f32x4;

// bf16 round-to-nearest-even split helpers (no NaN/Inf in this problem)
__device__ __forceinline__ unsigned short f2bf(float x) {
    unsigned u = __builtin_bit_cast(unsigned, x);
    u += 0x7fff + ((u >> 16) & 1);
    return (unsigned short)(u >> 16);
}
__device__ __forceinline__ float bf2f(unsigned short b) {
    unsigned u = ((unsigned)b) << 16;
    return __builtin_bit_cast(float, u);
}
// g(v) = (z - u) collapsed through v = x + u :  relu(v-0.1) - min(v,0.1)
__device__ __forceinline__ float g_of(float v) {
    return fmaxf(v - 0.1f, 0.0f) - fminf(v, 0.1f);
}

// ---------------------------------------------------------------------------
// K0: G = I + A*A^T in fp64 (Gd) + fp32 copy (Gf) for the sweep
// ---------------------------------------------------------------------------
__global__ __launch_bounds__(256) void g_kernel_d(const float* __restrict__ A,
                                                  double* __restrict__ Gd,
                                                  float* __restrict__ Gf) {
    __shared__ float arow[NATOMS];
    int i = blockIdx.x;
    for (int k = threadIdx.x; k < NATOMS; k += 256) arow[k] = A[i * NATOMS + k];
    __syncthreads();
    int j = threadIdx.x;
    const float* aj = A + j * NATOMS;
    double s = (i == j) ? 1.0 : 0.0;
#pragma unroll 4
    for (int k = 0; k < NATOMS; ++k) s += (double)arow[k] * (double)aj[k];
    Gd[i * NMEAS + j] = s;
    Gf[i * NMEAS + j] = (float)s;
}

// ---------------------------------------------------------------------------
// K1: SPD inverse of Gf (256x256) via scalar symmetric SWEEP (r5-proven,
// 255-283us). r6-r9 lesson: the register allocator pins 1024/512-thr kernels
// at 64/128 VGPR regardless of hints, spilling blocked-panel working sets —
// scalar form is the accepted local minimum.
// sweep(all pivots) = -G^{-1}; negate on store.
// ---------------------------------------------------------------------------
__global__ __launch_bounds__(1024) void sweep_inverse(const float* __restrict__ src,
                                                      float* __restrict__ dst) {
    __shared__ float s_dn[NMEAS];   // pivot column, row-indexed (uniform reads)
    __shared__ float s_dt[NMEAS];   // strided layout (conflict-free per-lane reads)
    int t = threadIdx.x;
    int rb = t & 31;
    int cb = t >> 5;
    float vals[8][8];
#pragma unroll
    for (int i = 0; i < 8; ++i) {
        const float* row = &src[(8 * rb + i) * NMEAS + 8 * cb];
        float4 a = *(const float4*)row;
        float4 b = *(const float4*)(row + 4);
        vals[i][0] = a.x; vals[i][1] = a.y; vals[i][2] = a.z; vals[i][3] = a.w;
        vals[i][4] = b.x; vals[i][5] = b.y; vals[i][6] = b.z; vals[i][7] = b.w;
    }
#pragma unroll 1
    for (int p = 0; p < NMEAS; ++p) {
        int pb = p >> 3, pi = p & 7;
        __syncthreads();
        if (cb == pb) {
#pragma unroll
            for (int i = 0; i < 8; ++i) {
                float v = vals[i][0];
#pragma unroll
                for (int j = 1; j < 8; ++j) if (pi == j) v = vals[i][j];
                s_dn[8 * rb + i] = v;
                s_dt[i * 32 + rb] = v;
            }
        }
        __syncthreads();
        float d   = s_dn[p];
        float inv = 1.0f / d;
        float rv[8], cv[8];
#pragma unroll
        for (int i = 0; i < 8; ++i) rv[i] = s_dt[i * 32 + rb];
#pragma unroll
        for (int j = 0; j < 8; ++j) cv[j] = s_dn[8 * cb + j] * inv;
#pragma unroll
        for (int i = 0; i < 8; ++i)
#pragma unroll
            for (int j = 0; j < 8; ++j) vals[i][j] -= rv[i] * cv[j];
        if (rb == pb) {
#pragma unroll
            for (int i = 0; i < 8; ++i) if (pi == i) {
#pragma unroll
                for (int j = 0; j < 8; ++j) vals[i][j] = cv[j];
            }
        }
        if (cb == pb) {
#pragma unroll
            for (int j = 0; j < 8; ++j) if (pi == j) {
#pragma unroll
                for (int i = 0; i < 8; ++i)
                    vals[i][j] = (rb == pb && pi == i) ? -inv : rv[i] * inv;
            }
        }
    }
#pragma unroll
    for (int i = 0; i < 8; ++i)
#pragma unroll
        for (int j = 0; j < 8; ++j)
            dst[(8 * rb + i) * NMEAS + 8 * cb + j] = -vals[i][j];
}

// ---------------------------------------------------------------------------
// fp64 Newton refinement:  P = Gd @ X ;  Xn = 2X - X @ P   (X input fp32/fp64)
// (fp32 Newton was the r3/r4 bug: cancellation noise ~cond(G)*eps32)
// ---------------------------------------------------------------------------
template <typename TB>
__global__ __launch_bounds__(256) void mm_gd(const double* __restrict__ Gd,
                                             const TB* __restrict__ X,
                                             double* __restrict__ P) {
    __shared__ __align__(16) double row[NMEAS];
    int i = blockIdx.x;
    row[threadIdx.x] = Gd[i * NMEAS + threadIdx.x];
    __syncthreads();
    int j = threadIdx.x;
    double s = 0.0;
#pragma unroll 4
    for (int k = 0; k < NMEAS; ++k) s += row[k] * (double)X[k * NMEAS + j];
    P[i * NMEAS + j] = s;
}

template <typename TB>
__global__ __launch_bounds__(256) void upd_newton(const TB* __restrict__ X,
                                                  const double* __restrict__ P,
                                                  double* __restrict__ Xn) {
    __shared__ __align__(16) double row[NMEAS];
    int i = blockIdx.x;
    row[threadIdx.x] = (double)X[i * NMEAS + threadIdx.x];
    __syncthreads();
    int j = threadIdx.x;
    double s = 0.0;
#pragma unroll 4
    for (int k = 0; k < NMEAS; ++k) s += row[k] * P[k * NMEAS + j];
    Xn[i * NMEAS + j] = 2.0 * row[j] - s;
}

// ---------------------------------------------------------------------------
// K2: Hd = X2d @ A   (fp64 [256][256] @ fp32 [256][512] -> fp64 [256][512])
// ---------------------------------------------------------------------------
__global__ __launch_bounds__(256) void h_kernel_d(const double* __restrict__ Gi,
                                                  const float* __restrict__ A,
                                                  double* __restrict__ H) {
    __shared__ __align__(16) double grow[NMEAS];
    int i = blockIdx.x;
    grow[threadIdx.x] = Gi[i * NMEAS + threadIdx.x];
    __syncthreads();
    int k0 = threadIdx.x;
    double s0 = 0.0, s1 = 0.0;
#pragma unroll 4
    for (int j = 0; j < NMEAS; ++j) {
        double g = grow[j];
        s0 += g * (double)A[j * NATOMS + k0];
        s1 += g * (double)A[j * NATOMS + k0 + 256];
    }
    H[i * NATOMS + k0] = s0;
    H[i * NATOMS + k0 + 256] = s1;
}

// ---------------------------------------------------------------------------
// K3: W = I - A^T @ Hd  (fp64 accumulate), stored as bf16 hi/lo split
// ---------------------------------------------------------------------------
__global__ __launch_bounds__(256) void w_kernel_d(const float* __restrict__ A,
                                                  const double* __restrict__ H,
                                                  unsigned short* __restrict__ Whg,
                                                  unsigned short* __restrict__ Wlg) {
    __shared__ __align__(16) double acol[NMEAS];
    int p = blockIdx.x;
    acol[threadIdx.x] = (double)A[threadIdx.x * NATOMS + p];
    __syncthreads();
    int q0 = threadIdx.x;
    double s0 = 0.0, s1 = 0.0;
#pragma unroll 4
    for (int m = 0; m < NMEAS; ++m) {
        double a = acol[m];
        s0 += a * H[m * NATOMS + q0];
        s1 += a * H[m * NATOMS + q0 + 256];
    }
    double w0 = ((p == q0)       ? 1.0 : 0.0) - s0;
    double w1 = ((p == q0 + 256) ? 1.0 : 0.0) - s1;
    unsigned short h0 = f2bf((float)w0), h1 = f2bf((float)w1);
    Whg[p * NATOMS + q0]       = h0;
    Wlg[p * NATOMS + q0]       = f2bf((float)(w0 - (double)bf2f(h0)));
    Whg[p * NATOMS + q0 + 256] = h1;
    Wlg[p * NATOMS + q0 + 256] = f2bf((float)(w1 - (double)bf2f(h1)));
}

// ---------------------------------------------------------------------------
// K4: Delta0 = AtY (= t_1, since t_0 = 0), stored split bf16 hi/lo,
//     TRANSPOSED to [4096 voxels][512 atoms] for k-contiguous reads.
// AtY[k][b] = sum_m A[m][k] * Y[b][m]
// ---------------------------------------------------------------------------
__global__ __launch_bounds__(256) void aty_kernel(const float* __restrict__ A,
                                                  const float* __restrict__ Y,
                                                  unsigned short* __restrict__ Dh0,
                                                  unsigned short* __restrict__ Dl0) {
    __shared__ __align__(16) float At[64][65];
    __shared__ __align__(16) float Yt[64][65];
    int b0 = blockIdx.x * 64, k0 = blockIdx.y * 64;
    int t = threadIdx.x, tx = t & 15, ty = t >> 4;
    float acc[4][4] = {};
    for (int m0 = 0; m0 < NMEAS; m0 += 64) {
        __syncthreads();
        {
            int kk = t & 63, mr = t >> 6;
#pragma unroll
            for (int p = 0; p < 16; ++p)
                At[mr + 4 * p][kk] = A[(m0 + mr + 4 * p) * NATOMS + k0 + kk];
            int mm = t & 63, br = t >> 6;
#pragma unroll
            for (int p = 0; p < 16; ++p)
                Yt[mm][br + 4 * p] = Y[(b0 + br + 4 * p) * NMEAS + m0 + mm];
        }
        __syncthreads();
#pragma unroll 4
        for (int m = 0; m < 64; ++m) {
            float av[4], yv[4];
#pragma unroll
            for (int i = 0; i < 4; ++i) av[i] = At[m][ty * 4 + i];
#pragma unroll
            for (int j = 0; j < 4; ++j) yv[j] = Yt[m][tx * 4 + j];
#pragma unroll
            for (int i = 0; i < 4; ++i)
#pragma unroll
                for (int j = 0; j < 4; ++j) acc[i][j] += av[i] * yv[j];
        }
    }
#pragma unroll
    for (int j = 0; j < 4; ++j) {
        int b = b0 + tx * 4 + j;
        s4v h4, l4;
#pragma unroll
        for (int i = 0; i < 4; ++i) {
            float f = acc[i][j];
            unsigned short h = f2bf(f);
            h4[i] = (short)h;
            l4[i] = (short)f2bf(f - bf2f(h));
        }
        *(s4v*)&Dh0[(long)b * NATOMS + k0 + ty * 4] = h4;
        *(s4v*)&Dl0[(long)b * NATOMS + k0 + ty * 4] = l4;
    }
}

// ---------------------------------------------------------------------------
// K5: PERSISTENT fused ADMM — all 30 iterations in one kernel.
// Insight: the iteration is voxel-separable (x[:,b] depends only on v[:,b]),
// so a block owning 32 voxels needs NO inter-block communication:
//   x, v live in REGISTERS (fragment layout), Delta in LDS, W streamed
//   from L2 (1 MB/block/iter), zero global x/v/Delta traffic, 1 launch.
// Per iter:  xacc = mfma(W, Delta, C-in=xacc)   [x IS the accumulator]
//            v' = x' + min(v,0.1); Delta' = g(v')-g(v) -> LDS bf16 h/l
// 3-term split GEMM (Wh*Dh + Wh*Dl + Wl*Dh) as in r5-r11 (proven).
// Grid 128 x 512thr (8 waves); wave wv owns m-tiles {4wv..4wv+3} x 2 n-tiles.
// Registers: xacc 32 + v 32 + transients ~ 110 < the 128 cap (r7-r9 lesson).
// LDS Delta [32][520] h+l = 66.5 KB; pitch 520 shorts -> 2-way alias (free),
// 16B-aligned rows (1040B pitch). Iter 0 reads Delta_0 = split(AtY) global.
// ---------------------------------------------------------------------------
__global__ __launch_bounds__(512) void admm_fused(
        const unsigned short* __restrict__ Whg,
        const unsigned short* __restrict__ Wlg,
        const unsigned short* __restrict__ D0h,
        const unsigned short* __restrict__ D0l,
        float* __restrict__ out) {
    __shared__ __align__(16) unsigned short Dh[32][520];
    __shared__ __align__(16) unsigned short Dl[32][520];

    const int t = threadIdx.x;
    const int lane = t & 63, wv = t >> 6;   // 8 waves
    const int ln = lane & 15, kg = lane >> 4;
    const long vb = (long)blockIdx.x * 32;  // this block's voxel base

    f32x4 xacc[4][2] = {};                  // x (= MFMA accumulator), [mt][nt]
    f32x4 vreg[4][2] = {};                  // v, same fragment layout

#pragma unroll 1
    for (int it = 0; it < NITER; ++it) {
        // ---- GEMM: xacc += W @ Delta  (C-in = x_{k-1})
#pragma unroll 1
        for (int kc = 0; kc < 16; ++kc) {
            const int ko = kc * 32 + kg * 8;
            s8v bh[2], bl[2];
            if (it == 0) {
#pragma unroll
                for (int nt = 0; nt < 2; ++nt) {
                    long r = (vb + nt * 16 + ln) * NATOMS + ko;
                    bh[nt] = *(const s8v*)&D0h[r];
                    bl[nt] = *(const s8v*)&D0l[r];
                }
            } else {
#pragma unroll
                for (int nt = 0; nt < 2; ++nt) {
                    bh[nt] = *(const s8v*)&Dh[nt * 16 + ln][ko];
                    bl[nt] = *(const s8v*)&Dl[nt * 16 + ln][ko];
                }
            }
#pragma unroll
            for (int mt = 0; mt < 4; ++mt) {
                const long mrow = (long)((wv * 4 + mt) * 16 + ln) * NATOMS + ko;
                s8v ah = *(const s8v*)&Whg[mrow];
                s8v al = *(const s8v*)&Wlg[mrow];
#pragma unroll
                for (int nt = 0; nt < 2; ++nt) {
                    xacc[mt][nt] = __builtin_amdgcn_mfma_f32_16x16x32_bf16(ah, bh[nt], xacc[mt][nt], 0, 0, 0);
                    xacc[mt][nt] = __builtin_amdgcn_mfma_f32_16x16x32_bf16(ah, bl[nt], xacc[mt][nt], 0, 0, 0);
                    xacc[mt][nt] = __builtin_amdgcn_mfma_f32_16x16x32_bf16(al, bh[nt], xacc[mt][nt], 0, 0, 0);
                }
            }
        }
        if (it == NITER - 1) break;         // xacc holds x_30
        __syncthreads();                    // all waves done reading Delta
        // ---- epilogue: v' = x + min(v,0.1); Delta' = g(v')-g(v) -> LDS
#pragma unroll
        for (int mt = 0; mt < 4; ++mt)
#pragma unroll
            for (int nt = 0; nt < 2; ++nt) {
                s4v h4, l4;
#pragma unroll
                for (int j = 0; j < 4; ++j) {
                    float xv = xacc[mt][nt][j];
                    float vp = vreg[mt][nt][j];          // v=0 at it=0 ✓
                    float vn = xv + fminf(vp, 0.1f);
                    float dlt = g_of(vn) - g_of(vp);
                    vreg[mt][nt][j] = vn;
                    unsigned short h = f2bf(dlt);
                    h4[j] = (short)h;
                    l4[j] = (short)f2bf(dlt - bf2f(h));
                }
                int nl = nt * 16 + ln;
                int m  = (wv * 4 + mt) * 16 + kg * 4;
                *(s4v*)&Dh[nl][m] = h4;
                *(s4v*)&Dl[nl][m] = l4;
            }
        __syncthreads();                    // Delta ready for next GEMM
    }
    // ---- final: out[b][k] = x_30[k][b]  (thread holds 4 contiguous m per frag)
#pragma unroll
    for (int mt = 0; mt < 4; ++mt)
#pragma unroll
        for (int nt = 0; nt < 2; ++nt) {
            long n = vb + nt * 16 + ln;
            int  m = (wv * 4 + mt) * 16 + kg * 4;
            *(f32x4*)&out[n * NATOMS + m] = xacc[mt][nt];
        }
}

// ---------------------------------------------------------------------------
extern "C" void kernel_launch(void* const* d_in, const int* in_sizes, int n_in,
                              void* d_out, int out_size, void* d_ws, size_t ws_size,
                              hipStream_t stream) {
    const float* Y = (const float*)d_in[0];   // [4096][256]
    const float* A = (const float*)d_in[1];   // [256][512]

    // ws layout (float units), lifetime-checked overlays (r3-r11 footprint).
    float* ws = (float*)d_ws;
    double* Gd  = (double*)(ws + 0);        // [0,131072)       dead after step 5
    float*  Gf  = ws + 131072;              // [131072,196608)  dead after sweep
    float*  X0f = ws + 196608;              // [196608,262144)  dead after step 4
    double* X1d = (double*)(ws + 262144);   // [262144,393216)  dead after step 6
    double* Pd  = (double*)(ws + 393216);   // [393216,524288)  dead after step 6
    double* X2d = (double*)(ws + 131072);   // overlays Gf+X0f (both dead)
    double* Hd  = (double*)(ws + 393216);   // [393216,655360) overlays Pd (dead)
    unsigned short* Whg = (unsigned short*)(ws + 0);        // overlays Gd (dead)
    unsigned short* Wlg = (unsigned short*)(ws + 131072);   // overlays X2d (dead after h)
    unsigned short* DAh = (unsigned short*)(ws + 2752512);  // Delta_0 hi
    unsigned short* DAl = (unsigned short*)(ws + 3801088);  // Delta_0 lo
    float* outp = (float*)d_out;

    g_kernel_d<<<256, 256, 0, stream>>>(A, Gd, Gf);                 // 1
    sweep_inverse<<<1, 1024, 0, stream>>>(Gf, X0f);                 // 2
    mm_gd<float><<<256, 256, 0, stream>>>(Gd, X0f, Pd);             // 3
    upd_newton<float><<<256, 256, 0, stream>>>(X0f, Pd, X1d);       // 4
    mm_gd<double><<<256, 256, 0, stream>>>(Gd, X1d, Pd);            // 5
    upd_newton<double><<<256, 256, 0, stream>>>(X1d, Pd, X2d);      // 6
    h_kernel_d<<<256, 256, 0, stream>>>(X2d, A, Hd);                // 7
    w_kernel_d<<<512, 256, 0, stream>>>(A, Hd, Whg, Wlg);           // 8
    aty_kernel<<<dim3(64, 8), 256, 0, stream>>>(A, Y, DAh, DAl);    // 9

    // 10: all 30 ADMM iterations, one persistent launch (128 blocks x 32 vox)
    admm_fused<<<128, 512, 0, stream>>>(Whg, Wlg, DAh, DAl, outp);
}

// Round 13
// 1350.673 us; speedup vs baseline: 1.0158x; 1.0158x over previous
//
#include <hip/hip_runtime.h>

// Problem constants (from reference setup_inputs)
#define NVOX   4096   // B voxels
#define NMEAS  256    // M measurements
#define NATOMS 512    // K atoms
#define NITER  30

typedef __attribute__((ext_vector_type(8))) short s8v;   // 8 bf16 (4 VGPR) MFMA frag
typedef __attribute__((ext_vector_type(4))) short s4v;
typedef __attribute__((ext_vector_type(4))) float f32x4;

// bf16 round-to-nearest-even split helpers (no NaN/Inf in this problem)
__device__ __forceinline__ unsigned short f2bf(float x) {
    unsigned u = __builtin_bit_cast(unsigned, x);
    u += 0x7fff + ((u >> 16) & 1);
    return (unsigned short)(u >> 16);
}
__device__ __forceinline__ float bf2f(unsigned short b) {
    unsigned u = ((unsigned)b) << 16;
    return __builtin_bit_cast(float, u);
}
// g(v) = (z - u) collapsed through v = x + u :  relu(v-0.1) - min(v,0.1)
__device__ __forceinline__ float g_of(float v) {
    return fmaxf(v - 0.1f, 0.0f) - fminf(v, 0.1f);
}

// ---------------------------------------------------------------------------
// K0: G = I + A*A^T in fp64 (Gd) + fp32 copy (Gf) for the sweep
// ---------------------------------------------------------------------------
__global__ __launch_bounds__(256) void g_kernel_d(const float* __restrict__ A,
                                                  double* __restrict__ Gd,
                                                  float* __restrict__ Gf) {
    __shared__ float arow[NATOMS];
    int i = blockIdx.x;
    for (int k = threadIdx.x; k < NATOMS; k += 256) arow[k] = A[i * NATOMS + k];
    __syncthreads();
    int j = threadIdx.x;
    const float* aj = A + j * NATOMS;
    double s = (i == j) ? 1.0 : 0.0;
#pragma unroll 4
    for (int k = 0; k < NATOMS; ++k) s += (double)arow[k] * (double)aj[k];
    Gd[i * NMEAS + j] = s;
    Gf[i * NMEAS + j] = (float)s;
}

// ---------------------------------------------------------------------------
// K1: SPD inverse of Gf (256x256) via scalar symmetric SWEEP (r5-proven,
// 255-283us). r6-r9 lesson: the register allocator pins 1024/512-thr kernels
// at 64/128 VGPR regardless of hints, spilling blocked-panel working sets —
// scalar form is the accepted local minimum.
// sweep(all pivots) = -G^{-1}; negate on store.
// ---------------------------------------------------------------------------
__global__ __launch_bounds__(1024) void sweep_inverse(const float* __restrict__ src,
                                                      float* __restrict__ dst) {
    __shared__ float s_dn[NMEAS];   // pivot column, row-indexed (uniform reads)
    __shared__ float s_dt[NMEAS];   // strided layout (conflict-free per-lane reads)
    int t = threadIdx.x;
    int rb = t & 31;
    int cb = t >> 5;
    float vals[8][8];
#pragma unroll
    for (int i = 0; i < 8; ++i) {
        const float* row = &src[(8 * rb + i) * NMEAS + 8 * cb];
        float4 a = *(const float4*)row;
        float4 b = *(const float4*)(row + 4);
        vals[i][0] = a.x; vals[i][1] = a.y; vals[i][2] = a.z; vals[i][3] = a.w;
        vals[i][4] = b.x; vals[i][5] = b.y; vals[i][6] = b.z; vals[i][7] = b.w;
    }
#pragma unroll 1
    for (int p = 0; p < NMEAS; ++p) {
        int pb = p >> 3, pi = p & 7;
        __syncthreads();
        if (cb == pb) {
#pragma unroll
            for (int i = 0; i < 8; ++i) {
                float v = vals[i][0];
#pragma unroll
                for (int j = 1; j < 8; ++j) if (pi == j) v = vals[i][j];
                s_dn[8 * rb + i] = v;
                s_dt[i * 32 + rb] = v;
            }
        }
        __syncthreads();
        float d   = s_dn[p];
        float inv = 1.0f / d;
        float rv[8], cv[8];
#pragma unroll
        for (int i = 0; i < 8; ++i) rv[i] = s_dt[i * 32 + rb];
#pragma unroll
        for (int j = 0; j < 8; ++j) cv[j] = s_dn[8 * cb + j] * inv;
#pragma unroll
        for (int i = 0; i < 8; ++i)
#pragma unroll
            for (int j = 0; j < 8; ++j) vals[i][j] -= rv[i] * cv[j];
        if (rb == pb) {
#pragma unroll
            for (int i = 0; i < 8; ++i) if (pi == i) {
#pragma unroll
                for (int j = 0; j < 8; ++j) vals[i][j] = cv[j];
            }
        }
        if (cb == pb) {
#pragma unroll
            for (int j = 0; j < 8; ++j) if (pi == j) {
#pragma unroll
                for (int i = 0; i < 8; ++i)
                    vals[i][j] = (rb == pb && pi == i) ? -inv : rv[i] * inv;
            }
        }
    }
#pragma unroll
    for (int i = 0; i < 8; ++i)
#pragma unroll
        for (int j = 0; j < 8; ++j)
            dst[(8 * rb + i) * NMEAS + 8 * cb + j] = -vals[i][j];
}

// ---------------------------------------------------------------------------
// fp64 Newton refinement:  P = Gd @ X ;  Xn = 2X - X @ P   (X input fp32/fp64)
// (fp32 Newton was the r3/r4 bug: cancellation noise ~cond(G)*eps32)
// ---------------------------------------------------------------------------
template <typename TB>
__global__ __launch_bounds__(256) void mm_gd(const double* __restrict__ Gd,
                                             const TB* __restrict__ X,
                                             double* __restrict__ P) {
    __shared__ __align__(16) double row[NMEAS];
    int i = blockIdx.x;
    row[threadIdx.x] = Gd[i * NMEAS + threadIdx.x];
    __syncthreads();
    int j = threadIdx.x;
    double s = 0.0;
#pragma unroll 4
    for (int k = 0; k < NMEAS; ++k) s += row[k] * (double)X[k * NMEAS + j];
    P[i * NMEAS + j] = s;
}

template <typename TB>
__global__ __launch_bounds__(256) void upd_newton(const TB* __restrict__ X,
                                                  const double* __restrict__ P,
                                                  double* __restrict__ Xn) {
    __shared__ __align__(16) double row[NMEAS];
    int i = blockIdx.x;
    row[threadIdx.x] = (double)X[i * NMEAS + threadIdx.x];
    __syncthreads();
    int j = threadIdx.x;
    double s = 0.0;
#pragma unroll 4
    for (int k = 0; k < NMEAS; ++k) s += row[k] * P[k * NMEAS + j];
    Xn[i * NMEAS + j] = 2.0 * row[j] - s;
}

// ---------------------------------------------------------------------------
// K2: Hd = X2d @ A   (fp64 [256][256] @ fp32 [256][512] -> fp64 [256][512])
// ---------------------------------------------------------------------------
__global__ __launch_bounds__(256) void h_kernel_d(const double* __restrict__ Gi,
                                                  const float* __restrict__ A,
                                                  double* __restrict__ H) {
    __shared__ __align__(16) double grow[NMEAS];
    int i = blockIdx.x;
    grow[threadIdx.x] = Gi[i * NMEAS + threadIdx.x];
    __syncthreads();
    int k0 = threadIdx.x;
    double s0 = 0.0, s1 = 0.0;
#pragma unroll 4
    for (int j = 0; j < NMEAS; ++j) {
        double g = grow[j];
        s0 += g * (double)A[j * NATOMS + k0];
        s1 += g * (double)A[j * NATOMS + k0 + 256];
    }
    H[i * NATOMS + k0] = s0;
    H[i * NATOMS + k0 + 256] = s1;
}

// ---------------------------------------------------------------------------
// K3: W = I - A^T @ Hd  (fp64 accumulate), stored as bf16 hi/lo split
// ---------------------------------------------------------------------------
__global__ __launch_bounds__(256) void w_kernel_d(const float* __restrict__ A,
                                                  const double* __restrict__ H,
                                                  unsigned short* __restrict__ Whg,
                                                  unsigned short* __restrict__ Wlg) {
    __shared__ __align__(16) double acol[NMEAS];
    int p = blockIdx.x;
    acol[threadIdx.x] = (double)A[threadIdx.x * NATOMS + p];
    __syncthreads();
    int q0 = threadIdx.x;
    double s0 = 0.0, s1 = 0.0;
#pragma unroll 4
    for (int m = 0; m < NMEAS; ++m) {
        double a = acol[m];
        s0 += a * H[m * NATOMS + q0];
        s1 += a * H[m * NATOMS + q0 + 256];
    }
    double w0 = ((p == q0)       ? 1.0 : 0.0) - s0;
    double w1 = ((p == q0 + 256) ? 1.0 : 0.0) - s1;
    unsigned short h0 = f2bf((float)w0), h1 = f2bf((float)w1);
    Whg[p * NATOMS + q0]       = h0;
    Wlg[p * NATOMS + q0]       = f2bf((float)(w0 - (double)bf2f(h0)));
    Whg[p * NATOMS + q0 + 256] = h1;
    Wlg[p * NATOMS + q0 + 256] = f2bf((float)(w1 - (double)bf2f(h1)));
}

// ---------------------------------------------------------------------------
// K4: Delta0 = AtY (= t_1, since t_0 = 0), stored split bf16 hi/lo,
//     TRANSPOSED to [4096 voxels][512 atoms] for k-contiguous reads.
// AtY[k][b] = sum_m A[m][k] * Y[b][m]
// ---------------------------------------------------------------------------
__global__ __launch_bounds__(256) void aty_kernel(const float* __restrict__ A,
                                                  const float* __restrict__ Y,
                                                  unsigned short* __restrict__ Dh0,
                                                  unsigned short* __restrict__ Dl0) {
    __shared__ __align__(16) float At[64][65];
    __shared__ __align__(16) float Yt[64][65];
    int b0 = blockIdx.x * 64, k0 = blockIdx.y * 64;
    int t = threadIdx.x, tx = t & 15, ty = t >> 4;
    float acc[4][4] = {};
    for (int m0 = 0; m0 < NMEAS; m0 += 64) {
        __syncthreads();
        {
            int kk = t & 63, mr = t >> 6;
#pragma unroll
            for (int p = 0; p < 16; ++p)
                At[mr + 4 * p][kk] = A[(m0 + mr + 4 * p) * NATOMS + k0 + kk];
            int mm = t & 63, br = t >> 6;
#pragma unroll
            for (int p = 0; p < 16; ++p)
                Yt[mm][br + 4 * p] = Y[(b0 + br + 4 * p) * NMEAS + m0 + mm];
        }
        __syncthreads();
#pragma unroll 4
        for (int m = 0; m < 64; ++m) {
            float av[4], yv[4];
#pragma unroll
            for (int i = 0; i < 4; ++i) av[i] = At[m][ty * 4 + i];
#pragma unroll
            for (int j = 0; j < 4; ++j) yv[j] = Yt[m][tx * 4 + j];
#pragma unroll
            for (int i = 0; i < 4; ++i)
#pragma unroll
                for (int j = 0; j < 4; ++j) acc[i][j] += av[i] * yv[j];
        }
    }
#pragma unroll
    for (int j = 0; j < 4; ++j) {
        int b = b0 + tx * 4 + j;
        s4v h4, l4;
#pragma unroll
        for (int i = 0; i < 4; ++i) {
            float f = acc[i][j];
            unsigned short h = f2bf(f);
            h4[i] = (short)h;
            l4[i] = (short)f2bf(f - bf2f(h));
        }
        *(s4v*)&Dh0[(long)b * NATOMS + k0 + ty * 4] = h4;
        *(s4v*)&Dl0[(long)b * NATOMS + k0 + ty * 4] = l4;
    }
}

// ---------------------------------------------------------------------------
// K5: PERSISTENT fused ADMM — all 30 iterations in one kernel.
// Voxel-separable: block owns 32 voxels, x/v in registers, Delta in LDS,
// W streamed from L2, zero global state traffic, 1 launch.
// r12 lesson: default allocation for a 512-thr block is 64 VGPR — the
// 64-reg persistent state (xacc+vreg) spilled to scratch and every MFMA
// round-tripped its accumulator through L2 (956us, MfmaUtil 8%).
// Fix: __launch_bounds__(512, 2) pins the allocator at 128 VGPR (hard
// evidence from r7/r8 on a 512-thr kernel); peak live set here is
// ~100-110 regs (state 64 + frags 24 + addressing) -> fits, no spill.
// Also: Delta_0 preloaded into LDS coalesced once (removes the divergent
// uncoalesced per-kc it==0 global path).
// Per iter:  xacc = mfma(W, Delta, C-in=xacc)  [x IS the accumulator]
//            v' = x' + min(v,0.1); Delta' = g(v')-g(v) -> LDS bf16 h/l
// 3-term split GEMM (Wh*Dh + Wh*Dl + Wl*Dh) as r5-r11 (proven).
// Grid 128 x 512thr (8 waves); wave wv owns m-tiles {4wv..4wv+3} x 2 n-tiles.
// LDS Delta [32][520] h+l = 66.5 KB (b128 lane spread audited uniform).
// ---------------------------------------------------------------------------
__global__ __launch_bounds__(512, 2) void admm_fused(
        const unsigned short* __restrict__ Whg,
        const unsigned short* __restrict__ Wlg,
        const unsigned short* __restrict__ D0h,
        const unsigned short* __restrict__ D0l,
        float* __restrict__ out) {
    __shared__ __align__(16) unsigned short Dh[32][520];
    __shared__ __align__(16) unsigned short Dl[32][520];

    const int t = threadIdx.x;
    const int lane = t & 63, wv = t >> 6;   // 8 waves
    const int ln = lane & 15, kg = lane >> 4;
    const long vb = (long)blockIdx.x * 32;  // this block's voxel base

    // ---- preload Delta_0 = split(AtY) into LDS, coalesced (once)
#pragma unroll
    for (int q = 0; q < 4; ++q) {
        int idx = q * 512 + t;              // 0..2047
        int row = idx >> 6;                 // 32 rows
        int ch  = idx & 63;                 // 64 x s8v chunks of 8 shorts
        long g = (vb + row) * NATOMS + ch * 8;
        *(s8v*)&Dh[row][ch * 8] = *(const s8v*)&D0h[g];
        *(s8v*)&Dl[row][ch * 8] = *(const s8v*)&D0l[g];
    }
    __syncthreads();

    f32x4 xacc[4][2] = {};                  // x (= MFMA accumulator), [mt][nt]
    f32x4 vreg[4][2] = {};                  // v, same fragment layout

#pragma unroll 1
    for (int it = 0; it < NITER; ++it) {
        // ---- GEMM: xacc += W @ Delta  (C-in = x_{k-1})
#pragma unroll 1
        for (int kc = 0; kc < 16; ++kc) {
            const int ko = kc * 32 + kg * 8;
            s8v bh[2], bl[2];
#pragma unroll
            for (int nt = 0; nt < 2; ++nt) {
                bh[nt] = *(const s8v*)&Dh[nt * 16 + ln][ko];
                bl[nt] = *(const s8v*)&Dl[nt * 16 + ln][ko];
            }
#pragma unroll
            for (int mt = 0; mt < 4; ++mt) {
                const long mrow = (long)((wv * 4 + mt) * 16 + ln) * NATOMS + ko;
                s8v ah = *(const s8v*)&Whg[mrow];
                s8v al = *(const s8v*)&Wlg[mrow];
#pragma unroll
                for (int nt = 0; nt < 2; ++nt) {
                    xacc[mt][nt] = __builtin_amdgcn_mfma_f32_16x16x32_bf16(ah, bh[nt], xacc[mt][nt], 0, 0, 0);
                    xacc[mt][nt] = __builtin_amdgcn_mfma_f32_16x16x32_bf16(ah, bl[nt], xacc[mt][nt], 0, 0, 0);
                    xacc[mt][nt] = __builtin_amdgcn_mfma_f32_16x16x32_bf16(al, bh[nt], xacc[mt][nt], 0, 0, 0);
                }
            }
        }
        if (it == NITER - 1) break;         // xacc holds x_30
        __syncthreads();                    // all waves done reading Delta
        // ---- epilogue: v' = x + min(v,0.1); Delta' = g(v')-g(v) -> LDS
#pragma unroll
        for (int mt = 0; mt < 4; ++mt)
#pragma unroll
            for (int nt = 0; nt < 2; ++nt) {
                s4v h4, l4;
#pragma unroll
                for (int j = 0; j < 4; ++j) {
                    float xv = xacc[mt][nt][j];
                    float vp = vreg[mt][nt][j];          // v=0 at it=0 ✓
                    float vn = xv + fminf(vp, 0.1f);
                    float dlt = g_of(vn) - g_of(vp);
                    vreg[mt][nt][j] = vn;
                    unsigned short h = f2bf(dlt);
                    h4[j] = (short)h;
                    l4[j] = (short)f2bf(dlt - bf2f(h));
                }
                int nl = nt * 16 + ln;
                int m  = (wv * 4 + mt) * 16 + kg * 4;
                *(s4v*)&Dh[nl][m] = h4;
                *(s4v*)&Dl[nl][m] = l4;
            }
        __syncthreads();                    // Delta ready for next GEMM
    }
    // ---- final: out[b][k] = x_30[k][b]  (thread holds 4 contiguous m per frag)
#pragma unroll
    for (int mt = 0; mt < 4; ++mt)
#pragma unroll
        for (int nt = 0; nt < 2; ++nt) {
            long n = vb + nt * 16 + ln;
            int  m = (wv * 4 + mt) * 16 + kg * 4;
            *(f32x4*)&out[n * NATOMS + m] = xacc[mt][nt];
        }
}

// ---------------------------------------------------------------------------
extern "C" void kernel_launch(void* const* d_in, const int* in_sizes, int n_in,
                              void* d_out, int out_size, void* d_ws, size_t ws_size,
                              hipStream_t stream) {
    const float* Y = (const float*)d_in[0];   // [4096][256]
    const float* A = (const float*)d_in[1];   // [256][512]

    // ws layout (float units), lifetime-checked overlays (r3-r12 footprint).
    float* ws = (float*)d_ws;
    double* Gd  = (double*)(ws + 0);        // [0,131072)       dead after step 5
    float*  Gf  = ws + 131072;              // [131072,196608)  dead after sweep
    float*  X0f = ws + 196608;              // [196608,262144)  dead after step 4
    double* X1d = (double*)(ws + 262144);   // [262144,393216)  dead after step 6
    double* Pd  = (double*)(ws + 393216);   // [393216,524288)  dead after step 6
    double* X2d = (double*)(ws + 131072);   // overlays Gf+X0f (both dead)
    double* Hd  = (double*)(ws + 393216);   // [393216,655360) overlays Pd (dead)
    unsigned short* Whg = (unsigned short*)(ws + 0);        // overlays Gd (dead)
    unsigned short* Wlg = (unsigned short*)(ws + 131072);   // overlays X2d (dead after h)
    unsigned short* DAh = (unsigned short*)(ws + 2752512);  // Delta_0 hi
    unsigned short* DAl = (unsigned short*)(ws + 3801088);  // Delta_0 lo
    float* outp = (float*)d_out;

    g_kernel_d<<<256, 256, 0, stream>>>(A, Gd, Gf);                 // 1
    sweep_inverse<<<1, 1024, 0, stream>>>(Gf, X0f);                 // 2
    mm_gd<float><<<256, 256, 0, stream>>>(Gd, X0f, Pd);             // 3
    upd_newton<float><<<256, 256, 0, stream>>>(X0f, Pd, X1d);       // 4
    mm_gd<double><<<256, 256, 0, stream>>>(Gd, X1d, Pd);            // 5
    upd_newton<double><<<256, 256, 0, stream>>>(X1d, Pd, X2d);      // 6
    h_kernel_d<<<256, 256, 0, stream>>>(X2d, A, Hd);                // 7
    w_kernel_d<<<512, 256, 0, stream>>>(A, Hd, Whg, Wlg);           // 8
    aty_kernel<<<dim3(64, 8), 256, 0, stream>>>(A, Y, DAh, DAl);    // 9

    // 10: all 30 ADMM iterations, one persistent launch (128 blocks x 32 vox)
    admm_fused<<<128, 512, 0, stream>>>(Whg, Wlg, DAh, DAl, outp);
}

// Round 14
// 1056.069 us; speedup vs baseline: 1.2991x; 1.2790x over previous
//
#include <hip/hip_runtime.h>

// Problem constants (from reference setup_inputs)
#define NVOX   4096   // B voxels
#define NMEAS  256    // M measurements
#define NATOMS 512    // K atoms
#define NITER  30

typedef __attribute__((ext_vector_type(8))) short s8v;   // 8 bf16 (4 VGPR) MFMA frag
typedef __attribute__((ext_vector_type(4))) short s4v;
typedef __attribute__((ext_vector_type(4))) float f32x4;

// bf16 round-to-nearest-even split helpers (no NaN/Inf in this problem)
__device__ __forceinline__ unsigned short f2bf(float x) {
    unsigned u = __builtin_bit_cast(unsigned, x);
    u += 0x7fff + ((u >> 16) & 1);
    return (unsigned short)(u >> 16);
}
__device__ __forceinline__ float bf2f(unsigned short b) {
    unsigned u = ((unsigned)b) << 16;
    return __builtin_bit_cast(float, u);
}
// g(v) = (z - u) collapsed through v = x + u :  relu(v-0.1) - min(v,0.1)
__device__ __forceinline__ float g_of(float v) {
    return fmaxf(v - 0.1f, 0.0f) - fminf(v, 0.1f);
}

// ---------------------------------------------------------------------------
// K0: G = I + A*A^T in fp64 (Gd) + fp32 copy (Gf) for the sweep
// ---------------------------------------------------------------------------
__global__ __launch_bounds__(256) void g_kernel_d(const float* __restrict__ A,
                                                  double* __restrict__ Gd,
                                                  float* __restrict__ Gf) {
    __shared__ float arow[NATOMS];
    int i = blockIdx.x;
    for (int k = threadIdx.x; k < NATOMS; k += 256) arow[k] = A[i * NATOMS + k];
    __syncthreads();
    int j = threadIdx.x;
    const float* aj = A + j * NATOMS;
    double s = (i == j) ? 1.0 : 0.0;
#pragma unroll 4
    for (int k = 0; k < NATOMS; ++k) s += (double)arow[k] * (double)aj[k];
    Gd[i * NMEAS + j] = s;
    Gf[i * NMEAS + j] = (float)s;
}

// ---------------------------------------------------------------------------
// K1: SPD inverse of Gf (256x256), symmetric SWEEP with pivot PAIRS (NB=2).
// r5 showed the scalar sweep is barrier-bound (2650 cyc/pivot vs ~130
// compute; 512 barrier-drains x 16 waves). r6-r9 showed register-blocked
// NB=4 variants spill (allocator pins 1024-thr kernels at 64 VGPR).
// NB=2 keeps the scalar form's tiny working set (m0/m1[8]=16 regs + 2x2
// inverse) but halves the barrier count: 128 steps x 2 barriers.
// All vals[] indices compile-time via guard-select on pair-slot (rule #20).
// Blocked-sweep algebra (NB=4 flavor) was validated end-to-end in r6.
// sweep(all pivots) = -G^{-1}; negate on store. Pivots: SPD Schur 2x2,
// det > 0, no pivoting needed.
// ---------------------------------------------------------------------------
__global__ __launch_bounds__(1024) void sweep_nb2(const float* __restrict__ src,
                                                  float* __restrict__ dst) {
    __shared__ float U0[NMEAS], U1[NMEAS];  // pivot-pair columns, row-indexed
    __shared__ float T0[NMEAS], T1[NMEAS];  // strided [i*32+rb] copies
    int t = threadIdx.x;
    int rb = t & 31;
    int cb = t >> 5;
    float vals[8][8];
#pragma unroll
    for (int i = 0; i < 8; ++i) {
        const float* row = &src[(8 * rb + i) * NMEAS + 8 * cb];
        float4 a = *(const float4*)row;
        float4 b = *(const float4*)(row + 4);
        vals[i][0] = a.x; vals[i][1] = a.y; vals[i][2] = a.z; vals[i][3] = a.w;
        vals[i][4] = b.x; vals[i][5] = b.y; vals[i][6] = b.z; vals[i][7] = b.w;
    }
#pragma unroll 1
    for (int s = 0; s < 128; ++s) {        // pivots 2s, 2s+1
        int pb = s >> 2;                   // pivot col-block [0,32)
        int sp = s & 3;                    // pair slot within block (cols 2sp,2sp+1)
        __syncthreads();
        if (cb == pb) {                    // publish the pivot-pair columns
#pragma unroll
            for (int pp = 0; pp < 4; ++pp) if (pp == sp) {
#pragma unroll
                for (int i = 0; i < 8; ++i) {
                    float a = vals[i][2 * pp], b = vals[i][2 * pp + 1];
                    U0[8 * rb + i] = a; T0[i * 32 + rb] = a;
                    U1[8 * rb + i] = b; T1[i * 32 + rb] = b;
                }
            }
        }
        __syncthreads();
        int p0 = 8 * pb + 2 * sp;
        // B = App^{-1}, App = [[a00,a01],[a10,a11]] (symmetric SPD 2x2)
        float a00 = U0[p0], a01 = U1[p0], a10 = U0[p0 + 1], a11 = U1[p0 + 1];
        float idet = 1.0f / (a00 * a11 - a01 * a10);
        float b00 = a11 * idet, b01 = -a01 * idet;
        float b10 = -a10 * idet, b11 = a00 * idet;
        float m0[8], m1[8];                // my rows' pivot-pair entries (saved)
#pragma unroll
        for (int i = 0; i < 8; ++i) { m0[i] = T0[i * 32 + rb]; m1[i] = T1[i * 32 + rb]; }
        // generic rank-2 update + pivot-row fixup
#pragma unroll
        for (int j = 0; j < 8; ++j) {
            float n0 = U0[8 * cb + j], n1 = U1[8 * cb + j];  // A[p][col] (symmetry)
            float e0 = b00 * n0 + b01 * n1;
            float e1 = b10 * n0 + b11 * n1;
#pragma unroll
            for (int i = 0; i < 8; ++i)
                vals[i][j] -= m0[i] * e0 + m1[i] * e1;
            if (rb == pb) {                // rows p0,p1 <- B * A[p,:]
#pragma unroll
                for (int pp = 0; pp < 4; ++pp) if (pp == sp) {
                    vals[2 * pp][j]     = e0;
                    vals[2 * pp + 1][j] = e1;
                }
            }
        }
        // pivot-col fixup: cols p0,p1 <- A[:,p] * B
        if (cb == pb) {
#pragma unroll
            for (int pp = 0; pp < 4; ++pp) if (pp == sp) {
#pragma unroll
                for (int i = 0; i < 8; ++i) {
                    vals[i][2 * pp]     = m0[i] * b00 + m1[i] * b10;
                    vals[i][2 * pp + 1] = m0[i] * b01 + m1[i] * b11;
                }
            }
        }
        // diagonal 2x2 block <- -B (last)
        if (rb == pb && cb == pb) {
#pragma unroll
            for (int pp = 0; pp < 4; ++pp) if (pp == sp) {
                vals[2 * pp][2 * pp]         = -b00;
                vals[2 * pp][2 * pp + 1]     = -b01;
                vals[2 * pp + 1][2 * pp]     = -b10;
                vals[2 * pp + 1][2 * pp + 1] = -b11;
            }
        }
    }
    // sweep(all) == -G^{-1}  ->  negate on store
#pragma unroll
    for (int i = 0; i < 8; ++i)
#pragma unroll
        for (int j = 0; j < 8; ++j)
            dst[(8 * rb + i) * NMEAS + 8 * cb + j] = -vals[i][j];
}

// ---------------------------------------------------------------------------
// fp64 Newton refinement:  P = Gd @ X ;  Xn = 2X - X @ P   (X input fp32/fp64)
// (fp32 Newton was the r3/r4 bug: cancellation noise ~cond(G)*eps32)
// ---------------------------------------------------------------------------
template <typename TB>
__global__ __launch_bounds__(256) void mm_gd(const double* __restrict__ Gd,
                                             const TB* __restrict__ X,
                                             double* __restrict__ P) {
    __shared__ __align__(16) double row[NMEAS];
    int i = blockIdx.x;
    row[threadIdx.x] = Gd[i * NMEAS + threadIdx.x];
    __syncthreads();
    int j = threadIdx.x;
    double s = 0.0;
#pragma unroll 4
    for (int k = 0; k < NMEAS; ++k) s += row[k] * (double)X[k * NMEAS + j];
    P[i * NMEAS + j] = s;
}

template <typename TB>
__global__ __launch_bounds__(256) void upd_newton(const TB* __restrict__ X,
                                                  const double* __restrict__ P,
                                                  double* __restrict__ Xn) {
    __shared__ __align__(16) double row[NMEAS];
    int i = blockIdx.x;
    row[threadIdx.x] = (double)X[i * NMEAS + threadIdx.x];
    __syncthreads();
    int j = threadIdx.x;
    double s = 0.0;
#pragma unroll 4
    for (int k = 0; k < NMEAS; ++k) s += row[k] * P[k * NMEAS + j];
    Xn[i * NMEAS + j] = 2.0 * row[j] - s;
}

// ---------------------------------------------------------------------------
// K2: Hd = X2d @ A   (fp64 [256][256] @ fp32 [256][512] -> fp64 [256][512])
// ---------------------------------------------------------------------------
__global__ __launch_bounds__(256) void h_kernel_d(const double* __restrict__ Gi,
                                                  const float* __restrict__ A,
                                                  double* __restrict__ H) {
    __shared__ __align__(16) double grow[NMEAS];
    int i = blockIdx.x;
    grow[threadIdx.x] = Gi[i * NMEAS + threadIdx.x];
    __syncthreads();
    int k0 = threadIdx.x;
    double s0 = 0.0, s1 = 0.0;
#pragma unroll 4
    for (int j = 0; j < NMEAS; ++j) {
        double g = grow[j];
        s0 += g * (double)A[j * NATOMS + k0];
        s1 += g * (double)A[j * NATOMS + k0 + 256];
    }
    H[i * NATOMS + k0] = s0;
    H[i * NATOMS + k0 + 256] = s1;
}

// ---------------------------------------------------------------------------
// K3: W = I - A^T @ Hd  (fp64 accumulate), stored as bf16 hi/lo split
// ---------------------------------------------------------------------------
__global__ __launch_bounds__(256) void w_kernel_d(const float* __restrict__ A,
                                                  const double* __restrict__ H,
                                                  unsigned short* __restrict__ Whg,
                                                  unsigned short* __restrict__ Wlg) {
    __shared__ __align__(16) double acol[NMEAS];
    int p = blockIdx.x;
    acol[threadIdx.x] = (double)A[threadIdx.x * NATOMS + p];
    __syncthreads();
    int q0 = threadIdx.x;
    double s0 = 0.0, s1 = 0.0;
#pragma unroll 4
    for (int m = 0; m < NMEAS; ++m) {
        double a = acol[m];
        s0 += a * H[m * NATOMS + q0];
        s1 += a * H[m * NATOMS + q0 + 256];
    }
    double w0 = ((p == q0)       ? 1.0 : 0.0) - s0;
    double w1 = ((p == q0 + 256) ? 1.0 : 0.0) - s1;
    unsigned short h0 = f2bf((float)w0), h1 = f2bf((float)w1);
    Whg[p * NATOMS + q0]       = h0;
    Wlg[p * NATOMS + q0]       = f2bf((float)(w0 - (double)bf2f(h0)));
    Whg[p * NATOMS + q0 + 256] = h1;
    Wlg[p * NATOMS + q0 + 256] = f2bf((float)(w1 - (double)bf2f(h1)));
}

// ---------------------------------------------------------------------------
// K4: Delta0 = AtY (= t_1, since t_0 = 0), stored split bf16 hi/lo,
//     TRANSPOSED to [4096 voxels][512 atoms] for k-contiguous staging.
// AtY[k][b] = sum_m A[m][k] * Y[b][m]
// ---------------------------------------------------------------------------
__global__ __launch_bounds__(256) void aty_kernel(const float* __restrict__ A,
                                                  const float* __restrict__ Y,
                                                  unsigned short* __restrict__ Dh0,
                                                  unsigned short* __restrict__ Dl0) {
    __shared__ __align__(16) float At[64][65];
    __shared__ __align__(16) float Yt[64][65];
    int b0 = blockIdx.x * 64, k0 = blockIdx.y * 64;
    int t = threadIdx.x, tx = t & 15, ty = t >> 4;
    float acc[4][4] = {};
    for (int m0 = 0; m0 < NMEAS; m0 += 64) {
        __syncthreads();
        {
            int kk = t & 63, mr = t >> 6;
#pragma unroll
            for (int p = 0; p < 16; ++p)
                At[mr + 4 * p][kk] = A[(m0 + mr + 4 * p) * NATOMS + k0 + kk];
            int mm = t & 63, br = t >> 6;
#pragma unroll
            for (int p = 0; p < 16; ++p)
                Yt[mm][br + 4 * p] = Y[(b0 + br + 4 * p) * NMEAS + m0 + mm];
        }
        __syncthreads();
#pragma unroll 4
        for (int m = 0; m < 64; ++m) {
            float av[4], yv[4];
#pragma unroll
            for (int i = 0; i < 4; ++i) av[i] = At[m][ty * 4 + i];
#pragma unroll
            for (int j = 0; j < 4; ++j) yv[j] = Yt[m][tx * 4 + j];
#pragma unroll
            for (int i = 0; i < 4; ++i)
#pragma unroll
                for (int j = 0; j < 4; ++j) acc[i][j] += av[i] * yv[j];
        }
    }
#pragma unroll
    for (int j = 0; j < 4; ++j) {
        int b = b0 + tx * 4 + j;
        s4v h4, l4;
#pragma unroll
        for (int i = 0; i < 4; ++i) {
            float f = acc[i][j];
            unsigned short h = f2bf(f);
            h4[i] = (short)h;
            l4[i] = (short)f2bf(f - bf2f(h));
        }
        *(s4v*)&Dh0[(long)b * NATOMS + k0 + ty * 4] = h4;
        *(s4v*)&Dl0[(long)b * NATOMS + k0 + ty * 4] = l4;
    }
}

// ---------------------------------------------------------------------------
// K5: one ADMM iteration, DELTA form, bf16-split MFMA, 3 terms
//   (Wh*Dh + Wh*Dl + Wl*Dh; dropped Wl*Dl <= 2^-18 rel):
//   dx = W @ Delta_in ; x_k = x_{k-1}+dx ; v_k = x_k + min(v_{k-1},0.1)
//   Delta_out = g(v_k)-g(v_{k-1}) -> split bf16 transposed [n][k]
// LAST: out[b][k] = x_{k-1} + dx  (transposed fp32 write)
// r9-PROVEN kernel, reverted verbatim (measured 20.6us/iter, PASSED; the
// r12/r13 fused-persistent design regressed to 31us/iter equivalent from
// the 64-VGPR allocator squeeze + half-idle grid and is abandoned).
// Tile: BM=64 x BN=64, BK=32, 256 thr (4 waves), grid 512 = 2 blocks/CU.
// ---------------------------------------------------------------------------
template <int FIRST, int LAST>
__global__ __launch_bounds__(256) void admm_delta(
        const unsigned short* __restrict__ Whg,
        const unsigned short* __restrict__ Wlg,
        const unsigned short* __restrict__ Dhg,
        const unsigned short* __restrict__ Dlg,
        float* __restrict__ xbuf,            // fp32 x [512][4096], in-place
        float* __restrict__ vbuf,            // fp32 v [512][4096], in-place (d_out)
        unsigned short* __restrict__ DhOut,
        unsigned short* __restrict__ DlOut,
        float* __restrict__ out) {
    __shared__ __align__(16) char smem[40960];
    unsigned short* Whs = (unsigned short*)smem;      // [2][64*40]
    unsigned short* Wls = Whs + 2 * 64 * 40;
    unsigned short* Dhs = Wls + 2 * 64 * 40;
    unsigned short* Dls = Dhs + 2 * 64 * 40;

    const int t = threadIdx.x;
    const int lane = t & 63, wv = t >> 6;
    const int ln = lane & 15, kg = lane >> 4;

    // XCD-aware bijective swizzle (grid 512 = 64x8, 8 XCDs, 64 blocks each)
    int bid = blockIdx.x + (blockIdx.y << 6);
    int xr = bid & 7, q = bid >> 3;
    int bx = xr * 8 + (q >> 3);          // [0,64)
    int by = q & 7;                      // [0,8)
    const int n0 = bx * 64, m0 = by * 64;

    const int wm = t >> 2, wslot = t & 3;     // staging: 64 rows x 4 slots
    const int tn = t >> 2, tslot = t & 3;

    f32x4 acc[4] = {};
    s8v rwh, rwl, rth, rtl;

#define GLOAD(kc)                                                             \
    {                                                                         \
        long ko = (long)(kc)*32;                                              \
        rwh = *(const s8v*)&Whg[(long)(m0 + wm) * NATOMS + ko + wslot * 8];   \
        rwl = *(const s8v*)&Wlg[(long)(m0 + wm) * NATOMS + ko + wslot * 8];   \
        rth = *(const s8v*)&Dhg[(long)(n0 + tn) * NATOMS + ko + tslot * 8];   \
        rtl = *(const s8v*)&Dlg[(long)(n0 + tn) * NATOMS + ko + tslot * 8];   \
    }
#define DSWRITE(b)                                                  \
    {                                                               \
        *(s8v*)&Whs[(b)*2560 + wm * 40 + wslot * 8] = rwh;          \
        *(s8v*)&Wls[(b)*2560 + wm * 40 + wslot * 8] = rwl;          \
        *(s8v*)&Dhs[(b)*2560 + tn * 40 + tslot * 8] = rth;          \
        *(s8v*)&Dls[(b)*2560 + tn * 40 + tslot * 8] = rtl;          \
    }

    GLOAD(0);
    DSWRITE(0);
#pragma unroll 1
    for (int c = 0; c < 16; ++c) {
        if (c < 15) GLOAD(c + 1);          // issue next chunk's loads early
        __syncthreads();                    // current buffer's ds_writes visible
        const int b = c & 1;
        const unsigned short* wh = &Whs[b * 2560];
        const unsigned short* wl = &Wls[b * 2560];
        const unsigned short* dh = &Dhs[b * 2560];
        const unsigned short* dl = &Dls[b * 2560];
        s8v ah[4], al[4], bh, bl;
#pragma unroll
        for (int mi = 0; mi < 4; ++mi) {
            ah[mi] = *(const s8v*)&wh[(mi * 16 + ln) * 40 + kg * 8];
            al[mi] = *(const s8v*)&wl[(mi * 16 + ln) * 40 + kg * 8];
        }
        {
            int r = wv * 16 + ln;
            bh = *(const s8v*)&dh[r * 40 + kg * 8];
            bl = *(const s8v*)&dl[r * 40 + kg * 8];
        }
#pragma unroll
        for (int mi = 0; mi < 4; ++mi) {
            acc[mi] = __builtin_amdgcn_mfma_f32_16x16x32_bf16(ah[mi], bh, acc[mi], 0, 0, 0);
            acc[mi] = __builtin_amdgcn_mfma_f32_16x16x32_bf16(ah[mi], bl, acc[mi], 0, 0, 0);
            acc[mi] = __builtin_amdgcn_mfma_f32_16x16x32_bf16(al[mi], bh, acc[mi], 0, 0, 0);
        }
        if (c < 15) DSWRITE((c + 1) & 1);  // prev use of that buffer done pre-barrier
    }
#undef GLOAD
#undef DSWRITE

    __syncthreads();                        // staging LDS dead; reuse as xT [64][68] f32
    float* xT = (float*)smem;

    if (!LAST) {
#pragma unroll
        for (int mi = 0; mi < 4; ++mi) {
            int nn = n0 + wv * 16 + ln;
            f32x4 dlt;
#pragma unroll
            for (int j = 0; j < 4; ++j) {
                int m = m0 + mi * 16 + kg * 4 + j;
                long idx = (long)m * NVOX + nn;
                float dx = acc[mi][j];
                float xn, vn, gold;
                if (FIRST) {
                    xn = dx; vn = xn; gold = 0.0f;   // x0=0, u0=0, v0=0
                } else {
                    xn = xbuf[idx] + dx;
                    float vp = vbuf[idx];
                    vn = xn + fminf(vp, 0.1f);
                    gold = g_of(vp);
                }
                xbuf[idx] = xn;
                vbuf[idx] = vn;
                dlt[j] = g_of(vn) - gold;
            }
            int nl = wv * 16 + ln;
            int ml = mi * 16 + kg * 4;
            *(f32x4*)&xT[nl * 68 + ml] = dlt;
        }
        __syncthreads();
        int nl = t >> 2, seg = t & 3;        // 64 rows x 16 m-cols per thread
#pragma unroll
        for (int q8 = 0; q8 < 2; ++q8) {
            s8v hv, lv;
#pragma unroll
            for (int e = 0; e < 8; ++e) {
                float f = xT[nl * 68 + seg * 16 + q8 * 8 + e];
                unsigned short h = f2bf(f);
                hv[e] = (short)h;
                lv[e] = (short)f2bf(f - bf2f(h));
            }
            *(s8v*)&DhOut[(long)(n0 + nl) * NATOMS + m0 + seg * 16 + q8 * 8] = hv;
            *(s8v*)&DlOut[(long)(n0 + nl) * NATOMS + m0 + seg * 16 + q8 * 8] = lv;
        }
    } else {
        // LAST: out[b][k] = x_{k-1}[k][b] + dx  (transposed fp32 write)
#pragma unroll
        for (int mi = 0; mi < 4; ++mi) {
            int nn = n0 + wv * 16 + ln;
            f32x4 tv;
#pragma unroll
            for (int j = 0; j < 4; ++j) {
                int m = m0 + mi * 16 + kg * 4 + j;
                tv[j] = xbuf[(long)m * NVOX + nn] + acc[mi][j];
            }
            int nl = wv * 16 + ln;
            int ml = mi * 16 + kg * 4;
            *(f32x4*)&xT[nl * 68 + ml] = tv;
        }
        __syncthreads();
        int nl = t >> 2, seg = t & 3;
#pragma unroll
        for (int q = 0; q < 4; ++q) {
            f32x4 v = *(const f32x4*)&xT[nl * 68 + seg * 16 + q * 4];
            *(f32x4*)&out[(long)(n0 + nl) * NATOMS + m0 + seg * 16 + q * 4] = v;
        }
    }
}

// ---------------------------------------------------------------------------
extern "C" void kernel_launch(void* const* d_in, const int* in_sizes, int n_in,
                              void* d_out, int out_size, void* d_ws, size_t ws_size,
                              hipStream_t stream) {
    const float* Y = (const float*)d_in[0];   // [4096][256]
    const float* A = (const float*)d_in[1];   // [256][512]

    // ws layout (float units), lifetime-checked overlays; total 6946816 floats
    // = 26.5 MiB (r3-r13 proven footprint).
    float* ws = (float*)d_ws;
    double* Gd  = (double*)(ws + 0);        // [0,131072)       dead after step 5
    float*  Gf  = ws + 131072;              // [131072,196608)  dead after sweep
    float*  X0f = ws + 196608;              // [196608,262144)  dead after step 4
    double* X1d = (double*)(ws + 262144);   // [262144,393216)  dead after step 6
    double* Pd  = (double*)(ws + 393216);   // [393216,524288)  dead after step 6
    double* X2d = (double*)(ws + 131072);   // overlays Gf+X0f (both dead)
    double* Hd  = (double*)(ws + 393216);   // [393216,655360) overlays Pd (dead)
    float*  xbuf = ws + 655360;             // [655360,2752512) fp32 x state
    unsigned short* Whg = (unsigned short*)(ws + 0);        // overlays Gd (dead)
    unsigned short* Wlg = (unsigned short*)(ws + 131072);   // overlays X2d (dead after h)
    unsigned short* DAh = (unsigned short*)(ws + 2752512);
    unsigned short* DAl = (unsigned short*)(ws + 3801088);
    unsigned short* DBh = (unsigned short*)(ws + 4849664);
    unsigned short* DBl = (unsigned short*)(ws + 5898240);  // end 6946816
    float* vbuf = (float*)d_out;   // v_k fp32, iters 1..29 (d_out as scratch)
    float* outp = (float*)d_out;   // final output, written by LAST iter only

    g_kernel_d<<<256, 256, 0, stream>>>(A, Gd, Gf);                 // 1
    sweep_nb2<<<1, 1024, 0, stream>>>(Gf, X0f);                     // 2
    mm_gd<float><<<256, 256, 0, stream>>>(Gd, X0f, Pd);             // 3
    upd_newton<float><<<256, 256, 0, stream>>>(X0f, Pd, X1d);       // 4
    mm_gd<double><<<256, 256, 0, stream>>>(Gd, X1d, Pd);            // 5
    upd_newton<double><<<256, 256, 0, stream>>>(X1d, Pd, X2d);      // 6
    h_kernel_d<<<256, 256, 0, stream>>>(X2d, A, Hd);                // 7
    w_kernel_d<<<512, 256, 0, stream>>>(A, Hd, Whg, Wlg);           // 8
    aty_kernel<<<dim3(64, 8), 256, 0, stream>>>(A, Y, DAh, DAl);    // 9

    dim3 ig(NVOX / 64, NATOMS / 64);  // (64, 8) = 512 blocks = 2/CU
    unsigned short *ch = DAh, *cl = DAl, *nh = DBh, *nl = DBl;
    // iter 1: Delta_0 = AtY; x1 = W*AtY; v1 = x1; Delta_1 = g(v1)
    admm_delta<1, 0><<<ig, 256, 0, stream>>>(Whg, Wlg, ch, cl, xbuf, vbuf, nh, nl, nullptr);
    { unsigned short* s; s = ch; ch = nh; nh = s; s = cl; cl = nl; nl = s; }
    for (int it = 2; it <= NITER - 1; ++it) {
        admm_delta<0, 0><<<ig, 256, 0, stream>>>(Whg, Wlg, ch, cl, xbuf, vbuf, nh, nl, nullptr);
        unsigned short* s; s = ch; ch = nh; nh = s; s = cl; cl = nl; nl = s;
    }
    // iter 30: x30 = x29 + W*Delta_29, written transposed to d_out
    admm_delta<0, 1><<<ig, 256, 0, stream>>>(Whg, Wlg, ch, cl, xbuf, vbuf, nullptr, nullptr, outp);
}

// Round 15
// 1005.062 us; speedup vs baseline: 1.3650x; 1.0508x over previous
//
#include <hip/hip_runtime.h>

// Problem constants (from reference setup_inputs)
#define NVOX   4096   // B voxels
#define NMEAS  256    // M measurements
#define NATOMS 512    // K atoms
#define NITER  30

typedef __attribute__((ext_vector_type(8))) short s8v;   // 8 bf16 (4 VGPR) MFMA frag
typedef __attribute__((ext_vector_type(4))) short s4v;
typedef __attribute__((ext_vector_type(4))) float f32x4;

// bf16 round-to-nearest-even split helpers (no NaN/Inf in this problem)
__device__ __forceinline__ unsigned short f2bf(float x) {
    unsigned u = __builtin_bit_cast(unsigned, x);
    u += 0x7fff + ((u >> 16) & 1);
    return (unsigned short)(u >> 16);
}
__device__ __forceinline__ float bf2f(unsigned short b) {
    unsigned u = ((unsigned)b) << 16;
    return __builtin_bit_cast(float, u);
}
// g(v) = (z - u) collapsed through v = x + u :  relu(v-0.1) - min(v,0.1)
__device__ __forceinline__ float g_of(float v) {
    return fmaxf(v - 0.1f, 0.0f) - fminf(v, 0.1f);
}

// ---------------------------------------------------------------------------
// K0: G = I + A*A^T in fp64 (Gd) + fp32 copy (Gf) for the sweep
// ---------------------------------------------------------------------------
__global__ __launch_bounds__(256) void g_kernel_d(const float* __restrict__ A,
                                                  double* __restrict__ Gd,
                                                  float* __restrict__ Gf) {
    __shared__ float arow[NATOMS];
    int i = blockIdx.x;
    for (int k = threadIdx.x; k < NATOMS; k += 256) arow[k] = A[i * NATOMS + k];
    __syncthreads();
    int j = threadIdx.x;
    const float* aj = A + j * NATOMS;
    double s = (i == j) ? 1.0 : 0.0;
#pragma unroll 4
    for (int k = 0; k < NATOMS; ++k) s += (double)arow[k] * (double)aj[k];
    Gd[i * NMEAS + j] = s;
    Gf[i * NMEAS + j] = (float)s;
}

// ---------------------------------------------------------------------------
// K1: SPD inverse of Gf (256x256) via scalar symmetric SWEEP — r5-proven,
// 283us, PASSED repeatedly. STRUCTURAL FLOOR: r6/r7/r9 (blocked NB=4) and
// r14 (NB=2) all spilled — the allocator pins 1024-thr kernels at <=64 VGPR
// and any extra per-step state costs more in scratch than it saves in
// barriers. Accepted local minimum. sweep(all) = -G^{-1}; negate on store.
// ---------------------------------------------------------------------------
__global__ __launch_bounds__(1024) void sweep_inverse(const float* __restrict__ src,
                                                      float* __restrict__ dst) {
    __shared__ float s_dn[NMEAS];   // pivot column, row-indexed (uniform reads)
    __shared__ float s_dt[NMEAS];   // strided layout (conflict-free per-lane reads)
    int t = threadIdx.x;
    int rb = t & 31;
    int cb = t >> 5;
    float vals[8][8];
#pragma unroll
    for (int i = 0; i < 8; ++i) {
        const float* row = &src[(8 * rb + i) * NMEAS + 8 * cb];
        float4 a = *(const float4*)row;
        float4 b = *(const float4*)(row + 4);
        vals[i][0] = a.x; vals[i][1] = a.y; vals[i][2] = a.z; vals[i][3] = a.w;
        vals[i][4] = b.x; vals[i][5] = b.y; vals[i][6] = b.z; vals[i][7] = b.w;
    }
#pragma unroll 1
    for (int p = 0; p < NMEAS; ++p) {
        int pb = p >> 3, pi = p & 7;
        __syncthreads();
        if (cb == pb) {
#pragma unroll
            for (int i = 0; i < 8; ++i) {
                float v = vals[i][0];
#pragma unroll
                for (int j = 1; j < 8; ++j) if (pi == j) v = vals[i][j];
                s_dn[8 * rb + i] = v;
                s_dt[i * 32 + rb] = v;
            }
        }
        __syncthreads();
        float d   = s_dn[p];
        float inv = 1.0f / d;
        float rv[8], cv[8];
#pragma unroll
        for (int i = 0; i < 8; ++i) rv[i] = s_dt[i * 32 + rb];
#pragma unroll
        for (int j = 0; j < 8; ++j) cv[j] = s_dn[8 * cb + j] * inv;
#pragma unroll
        for (int i = 0; i < 8; ++i)
#pragma unroll
            for (int j = 0; j < 8; ++j) vals[i][j] -= rv[i] * cv[j];
        if (rb == pb) {
#pragma unroll
            for (int i = 0; i < 8; ++i) if (pi == i) {
#pragma unroll
                for (int j = 0; j < 8; ++j) vals[i][j] = cv[j];
            }
        }
        if (cb == pb) {
#pragma unroll
            for (int j = 0; j < 8; ++j) if (pi == j) {
#pragma unroll
                for (int i = 0; i < 8; ++i)
                    vals[i][j] = (rb == pb && pi == i) ? -inv : rv[i] * inv;
            }
        }
    }
#pragma unroll
    for (int i = 0; i < 8; ++i)
#pragma unroll
        for (int j = 0; j < 8; ++j)
            dst[(8 * rb + i) * NMEAS + 8 * cb + j] = -vals[i][j];
}

// ---------------------------------------------------------------------------
// fp64 Newton refinement:  P = Gd @ X ;  Xn = 2X - X @ P   (X input fp32/fp64)
// (fp32 Newton was the r3/r4 bug: cancellation noise ~cond(G)*eps32)
// ---------------------------------------------------------------------------
template <typename TB>
__global__ __launch_bounds__(256) void mm_gd(const double* __restrict__ Gd,
                                             const TB* __restrict__ X,
                                             double* __restrict__ P) {
    __shared__ __align__(16) double row[NMEAS];
    int i = blockIdx.x;
    row[threadIdx.x] = Gd[i * NMEAS + threadIdx.x];
    __syncthreads();
    int j = threadIdx.x;
    double s = 0.0;
#pragma unroll 4
    for (int k = 0; k < NMEAS; ++k) s += row[k] * (double)X[k * NMEAS + j];
    P[i * NMEAS + j] = s;
}

template <typename TB>
__global__ __launch_bounds__(256) void upd_newton(const TB* __restrict__ X,
                                                  const double* __restrict__ P,
                                                  double* __restrict__ Xn) {
    __shared__ __align__(16) double row[NMEAS];
    int i = blockIdx.x;
    row[threadIdx.x] = (double)X[i * NMEAS + threadIdx.x];
    __syncthreads();
    int j = threadIdx.x;
    double s = 0.0;
#pragma unroll 4
    for (int k = 0; k < NMEAS; ++k) s += row[k] * P[k * NMEAS + j];
    Xn[i * NMEAS + j] = 2.0 * row[j] - s;
}

// ---------------------------------------------------------------------------
// K2: Hd = X2d @ A   (fp64 [256][256] @ fp32 [256][512] -> fp64 [256][512])
// ---------------------------------------------------------------------------
__global__ __launch_bounds__(256) void h_kernel_d(const double* __restrict__ Gi,
                                                  const float* __restrict__ A,
                                                  double* __restrict__ H) {
    __shared__ __align__(16) double grow[NMEAS];
    int i = blockIdx.x;
    grow[threadIdx.x] = Gi[i * NMEAS + threadIdx.x];
    __syncthreads();
    int k0 = threadIdx.x;
    double s0 = 0.0, s1 = 0.0;
#pragma unroll 4
    for (int j = 0; j < NMEAS; ++j) {
        double g = grow[j];
        s0 += g * (double)A[j * NATOMS + k0];
        s1 += g * (double)A[j * NATOMS + k0 + 256];
    }
    H[i * NATOMS + k0] = s0;
    H[i * NATOMS + k0 + 256] = s1;
}

// ---------------------------------------------------------------------------
// K3: W = I - A^T @ Hd  (fp64 accumulate), stored as bf16 hi/lo split
// ---------------------------------------------------------------------------
__global__ __launch_bounds__(256) void w_kernel_d(const float* __restrict__ A,
                                                  const double* __restrict__ H,
                                                  unsigned short* __restrict__ Whg,
                                                  unsigned short* __restrict__ Wlg) {
    __shared__ __align__(16) double acol[NMEAS];
    int p = blockIdx.x;
    acol[threadIdx.x] = (double)A[threadIdx.x * NATOMS + p];
    __syncthreads();
    int q0 = threadIdx.x;
    double s0 = 0.0, s1 = 0.0;
#pragma unroll 4
    for (int m = 0; m < NMEAS; ++m) {
        double a = acol[m];
        s0 += a * H[m * NATOMS + q0];
        s1 += a * H[m * NATOMS + q0 + 256];
    }
    double w0 = ((p == q0)       ? 1.0 : 0.0) - s0;
    double w1 = ((p == q0 + 256) ? 1.0 : 0.0) - s1;
    unsigned short h0 = f2bf((float)w0), h1 = f2bf((float)w1);
    Whg[p * NATOMS + q0]       = h0;
    Wlg[p * NATOMS + q0]       = f2bf((float)(w0 - (double)bf2f(h0)));
    Whg[p * NATOMS + q0 + 256] = h1;
    Wlg[p * NATOMS + q0 + 256] = f2bf((float)(w1 - (double)bf2f(h1)));
}

// ---------------------------------------------------------------------------
// K4: Delta0 = AtY (= t_1, since t_0 = 0), stored split bf16 hi/lo,
//     TRANSPOSED to [4096 voxels][512 atoms] for k-contiguous staging.
// AtY[k][b] = sum_m A[m][k] * Y[b][m]
// ---------------------------------------------------------------------------
__global__ __launch_bounds__(256) void aty_kernel(const float* __restrict__ A,
                                                  const float* __restrict__ Y,
                                                  unsigned short* __restrict__ Dh0,
                                                  unsigned short* __restrict__ Dl0) {
    __shared__ __align__(16) float At[64][65];
    __shared__ __align__(16) float Yt[64][65];
    int b0 = blockIdx.x * 64, k0 = blockIdx.y * 64;
    int t = threadIdx.x, tx = t & 15, ty = t >> 4;
    float acc[4][4] = {};
    for (int m0 = 0; m0 < NMEAS; m0 += 64) {
        __syncthreads();
        {
            int kk = t & 63, mr = t >> 6;
#pragma unroll
            for (int p = 0; p < 16; ++p)
                At[mr + 4 * p][kk] = A[(m0 + mr + 4 * p) * NATOMS + k0 + kk];
            int mm = t & 63, br = t >> 6;
#pragma unroll
            for (int p = 0; p < 16; ++p)
                Yt[mm][br + 4 * p] = Y[(b0 + br + 4 * p) * NMEAS + m0 + mm];
        }
        __syncthreads();
#pragma unroll 4
        for (int m = 0; m < 64; ++m) {
            float av[4], yv[4];
#pragma unroll
            for (int i = 0; i < 4; ++i) av[i] = At[m][ty * 4 + i];
#pragma unroll
            for (int j = 0; j < 4; ++j) yv[j] = Yt[m][tx * 4 + j];
#pragma unroll
            for (int i = 0; i < 4; ++i)
#pragma unroll
                for (int j = 0; j < 4; ++j) acc[i][j] += av[i] * yv[j];
        }
    }
#pragma unroll
    for (int j = 0; j < 4; ++j) {
        int b = b0 + tx * 4 + j;
        s4v h4, l4;
#pragma unroll
        for (int i = 0; i < 4; ++i) {
            float f = acc[i][j];
            unsigned short h = f2bf(f);
            h4[i] = (short)h;
            l4[i] = (short)f2bf(f - bf2f(h));
        }
        *(s4v*)&Dh0[(long)b * NATOMS + k0 + ty * 4] = h4;
        *(s4v*)&Dl0[(long)b * NATOMS + k0 + ty * 4] = l4;
    }
}

// ---------------------------------------------------------------------------
// K5: one ADMM iteration, DELTA form, bf16-split MFMA, 3 terms
//   (Wh*Dh + Wh*Dl + Wl*Dh; dropped Wl*Dl <= 2^-18 rel):
//   dx = W @ Delta_in ; x_k = x_{k-1}+dx ; v_k = x_k + min(v_{k-1},0.1)
//   Delta_out = g(v_k)-g(v_{k-1})
// GEMM core == r9-proven (BM=64 x BN=64, BK=32, 256 thr, grid 512 = 2/CU).
// r15 change (Guideline 13): x/v stored [vox][atom] (same layout as Delta)
// — the MFMA C/D fragment holds 4 CONSECUTIVE m for fixed voxel, so every
// x/v access becomes one float4 and Delta-out a direct s4v write, removing
// the 32 scalar accesses + LDS transpose bounce + 1 barrier per epilogue.
// Arithmetic values/order identical -> absmax bit-identical.
// LAST: out[b][k] = x_{k-1} + dx written float4 direct (out layout matches).
// ---------------------------------------------------------------------------
template <int FIRST, int LAST>
__global__ __launch_bounds__(256) void admm_delta(
        const unsigned short* __restrict__ Whg,
        const unsigned short* __restrict__ Wlg,
        const unsigned short* __restrict__ Dhg,
        const unsigned short* __restrict__ Dlg,
        float* __restrict__ xbuf,            // fp32 x [vox][atom], in-place
        float* __restrict__ vbuf,            // fp32 v [vox][atom], in-place (d_out)
        unsigned short* __restrict__ DhOut,  // [vox][atom]
        unsigned short* __restrict__ DlOut,
        float* __restrict__ out) {
    __shared__ __align__(16) char smem[40960];
    unsigned short* Whs = (unsigned short*)smem;      // [2][64*40]
    unsigned short* Wls = Whs + 2 * 64 * 40;
    unsigned short* Dhs = Wls + 2 * 64 * 40;
    unsigned short* Dls = Dhs + 2 * 64 * 40;

    const int t = threadIdx.x;
    const int lane = t & 63, wv = t >> 6;
    const int ln = lane & 15, kg = lane >> 4;

    // XCD-aware bijective swizzle (grid 512 = 64x8, 8 XCDs, 64 blocks each)
    int bid = blockIdx.x + (blockIdx.y << 6);
    int xr = bid & 7, q = bid >> 3;
    int bx = xr * 8 + (q >> 3);          // [0,64)
    int by = q & 7;                      // [0,8)
    const int n0 = bx * 64, m0 = by * 64;

    const int wm = t >> 2, wslot = t & 3;     // staging: 64 rows x 4 slots
    const int tn = t >> 2, tslot = t & 3;

    f32x4 acc[4] = {};
    s8v rwh, rwl, rth, rtl;

#define GLOAD(kc)                                                             \
    {                                                                         \
        long ko = (long)(kc)*32;                                              \
        rwh = *(const s8v*)&Whg[(long)(m0 + wm) * NATOMS + ko + wslot * 8];   \
        rwl = *(const s8v*)&Wlg[(long)(m0 + wm) * NATOMS + ko + wslot * 8];   \
        rth = *(const s8v*)&Dhg[(long)(n0 + tn) * NATOMS + ko + tslot * 8];   \
        rtl = *(const s8v*)&Dlg[(long)(n0 + tn) * NATOMS + ko + tslot * 8];   \
    }
#define DSWRITE(b)                                                  \
    {                                                               \
        *(s8v*)&Whs[(b)*2560 + wm * 40 + wslot * 8] = rwh;          \
        *(s8v*)&Wls[(b)*2560 + wm * 40 + wslot * 8] = rwl;          \
        *(s8v*)&Dhs[(b)*2560 + tn * 40 + tslot * 8] = rth;          \
        *(s8v*)&Dls[(b)*2560 + tn * 40 + tslot * 8] = rtl;          \
    }

    GLOAD(0);
    DSWRITE(0);
#pragma unroll 1
    for (int c = 0; c < 16; ++c) {
        if (c < 15) GLOAD(c + 1);          // issue next chunk's loads early
        __syncthreads();                    // current buffer's ds_writes visible
        const int b = c & 1;
        const unsigned short* wh = &Whs[b * 2560];
        const unsigned short* wl = &Wls[b * 2560];
        const unsigned short* dh = &Dhs[b * 2560];
        const unsigned short* dl = &Dls[b * 2560];
        s8v ah[4], al[4], bh, bl;
#pragma unroll
        for (int mi = 0; mi < 4; ++mi) {
            ah[mi] = *(const s8v*)&wh[(mi * 16 + ln) * 40 + kg * 8];
            al[mi] = *(const s8v*)&wl[(mi * 16 + ln) * 40 + kg * 8];
        }
        {
            int r = wv * 16 + ln;
            bh = *(const s8v*)&dh[r * 40 + kg * 8];
            bl = *(const s8v*)&dl[r * 40 + kg * 8];
        }
#pragma unroll
        for (int mi = 0; mi < 4; ++mi) {
            acc[mi] = __builtin_amdgcn_mfma_f32_16x16x32_bf16(ah[mi], bh, acc[mi], 0, 0, 0);
            acc[mi] = __builtin_amdgcn_mfma_f32_16x16x32_bf16(ah[mi], bl, acc[mi], 0, 0, 0);
            acc[mi] = __builtin_amdgcn_mfma_f32_16x16x32_bf16(al[mi], bh, acc[mi], 0, 0, 0);
        }
        if (c < 15) DSWRITE((c + 1) & 1);  // prev use of that buffer done pre-barrier
    }
#undef GLOAD
#undef DSWRITE

    // ---- epilogue: fragment (voxel nn, 4 consecutive m) -> float4/s4v direct
    const long nn = n0 + wv * 16 + ln;
    if (!LAST) {
#pragma unroll
        for (int mi = 0; mi < 4; ++mi) {
            long base = nn * NATOMS + m0 + mi * 16 + kg * 4;
            f32x4 xo, vo;
            if (!FIRST) {
                xo = *(const f32x4*)&xbuf[base];
                vo = *(const f32x4*)&vbuf[base];
            }
            f32x4 xn, vn;
            s4v h4, l4;
#pragma unroll
            for (int j = 0; j < 4; ++j) {
                float dx = acc[mi][j];
                float x, vnj, gold;
                if (FIRST) {
                    x = dx; vnj = x; gold = 0.0f;        // x0=0, v0=0
                } else {
                    x = xo[j] + dx;
                    vnj = x + fminf(vo[j], 0.1f);
                    gold = g_of(vo[j]);
                }
                float dlt = g_of(vnj) - gold;
                xn[j] = x; vn[j] = vnj;
                unsigned short h = f2bf(dlt);
                h4[j] = (short)h;
                l4[j] = (short)f2bf(dlt - bf2f(h));
            }
            *(f32x4*)&xbuf[base] = xn;
            *(f32x4*)&vbuf[base] = vn;
            *(s4v*)&DhOut[base] = h4;
            *(s4v*)&DlOut[base] = l4;
        }
    } else {
        // LAST: out[b][k] = x_{k-1} + dx  (float4 direct, layout matches)
#pragma unroll
        for (int mi = 0; mi < 4; ++mi) {
            long base = nn * NATOMS + m0 + mi * 16 + kg * 4;
            f32x4 xo = *(const f32x4*)&xbuf[base];
            f32x4 r;
#pragma unroll
            for (int j = 0; j < 4; ++j) r[j] = xo[j] + acc[mi][j];
            *(f32x4*)&out[base] = r;
        }
    }
}

// ---------------------------------------------------------------------------
extern "C" void kernel_launch(void* const* d_in, const int* in_sizes, int n_in,
                              void* d_out, int out_size, void* d_ws, size_t ws_size,
                              hipStream_t stream) {
    const float* Y = (const float*)d_in[0];   // [4096][256]
    const float* A = (const float*)d_in[1];   // [256][512]

    // ws layout (float units), lifetime-checked overlays; total 6946816 floats
    // = 26.5 MiB (r3-r14 proven footprint).
    float* ws = (float*)d_ws;
    double* Gd  = (double*)(ws + 0);        // [0,131072)       dead after step 5
    float*  Gf  = ws + 131072;              // [131072,196608)  dead after sweep
    float*  X0f = ws + 196608;              // [196608,262144)  dead after step 4
    double* X1d = (double*)(ws + 262144);   // [262144,393216)  dead after step 6
    double* Pd  = (double*)(ws + 393216);   // [393216,524288)  dead after step 6
    double* X2d = (double*)(ws + 131072);   // overlays Gf+X0f (both dead)
    double* Hd  = (double*)(ws + 393216);   // [393216,655360) overlays Pd (dead)
    float*  xbuf = ws + 655360;             // [655360,2752512) fp32 x state
    unsigned short* Whg = (unsigned short*)(ws + 0);        // overlays Gd (dead)
    unsigned short* Wlg = (unsigned short*)(ws + 131072);   // overlays X2d (dead after h)
    unsigned short* DAh = (unsigned short*)(ws + 2752512);
    unsigned short* DAl = (unsigned short*)(ws + 3801088);
    unsigned short* DBh = (unsigned short*)(ws + 4849664);
    unsigned short* DBl = (unsigned short*)(ws + 5898240);  // end 6946816
    float* vbuf = (float*)d_out;   // v_k fp32, iters 1..29 (d_out as scratch)
    float* outp = (float*)d_out;   // final output, written by LAST iter only

    g_kernel_d<<<256, 256, 0, stream>>>(A, Gd, Gf);                 // 1
    sweep_inverse<<<1, 1024, 0, stream>>>(Gf, X0f);                 // 2
    mm_gd<float><<<256, 256, 0, stream>>>(Gd, X0f, Pd);             // 3
    upd_newton<float><<<256, 256, 0, stream>>>(X0f, Pd, X1d);       // 4
    mm_gd<double><<<256, 256, 0, stream>>>(Gd, X1d, Pd);            // 5
    upd_newton<double><<<256, 256, 0, stream>>>(X1d, Pd, X2d);      // 6
    h_kernel_d<<<256, 256, 0, stream>>>(X2d, A, Hd);                // 7
    w_kernel_d<<<512, 256, 0, stream>>>(A, Hd, Whg, Wlg);           // 8
    aty_kernel<<<dim3(64, 8), 256, 0, stream>>>(A, Y, DAh, DAl);    // 9

    dim3 ig(NVOX / 64, NATOMS / 64);  // (64, 8) = 512 blocks = 2/CU
    unsigned short *ch = DAh, *cl = DAl, *nh = DBh, *nl = DBl;
    // iter 1: Delta_0 = AtY; x1 = W*AtY; v1 = x1; Delta_1 = g(v1)
    admm_delta<1, 0><<<ig, 256, 0, stream>>>(Whg, Wlg, ch, cl, xbuf, vbuf, nh, nl, nullptr);
    { unsigned short* s; s = ch; ch = nh; nh = s; s = cl; cl = nl; nl = s; }
    for (int it = 2; it <= NITER - 1; ++it) {
        admm_delta<0, 0><<<ig, 256, 0, stream>>>(Whg, Wlg, ch, cl, xbuf, vbuf, nh, nl, nullptr);
        unsigned short* s; s = ch; ch = nh; nh = s; s = cl; cl = nl; nl = s;
    }
    // iter 30: x30 = x29 + W*Delta_29, written to d_out (float4 direct)
    admm_delta<0, 1><<<ig, 256, 0, stream>>>(Whg, Wlg, ch, cl, xbuf, vbuf, nullptr, nullptr, outp);
}